// Round 5
// baseline (897.250 us; speedup 1.0000x reference)
//
#include <hip/hip_runtime.h>
#include <math.h>

#define B_ 8
#define N_ 2048
#define C_ 256
#define TOK (B_*N_)
#define PFD 4   // scan prefetch depth (steps)

struct GArgs {
  const float* W[6];
  const float* bias[6];
  float* outQ; float* outK; float* outV; float* outA; float* outB; float* outO;
};

// ---------------- DPP cross-lane reduction helpers (all-VALU, no DS) -------
template<int CTRL>
__device__ __forceinline__ float dpp_add(float x) {
  int r = __builtin_amdgcn_update_dpp(0, __float_as_int(x), CTRL, 0xF, 0xF, true);
  return x + __int_as_float(r);
}
// Sum across each aligned 16-lane group; result broadcast to all 16 lanes.
__device__ __forceinline__ float red16(float x) {
  x = dpp_add<0xB1>(x);   // quad_perm [1,0,3,2]  (xor 1)
  x = dpp_add<0x4E>(x);   // quad_perm [2,3,0,1]  (xor 2)
  x = dpp_add<0x140>(x);  // row_mirror           (xor 15)
  x = dpp_add<0x141>(x);  // row_half_mirror      (xor 7)
  return x;
}
// Full 64-lane sum -> scalar (valid in all lanes via readlane).
__device__ __forceinline__ float red64(float x) {
  x = red16(x);
  x = dpp_add<0x142>(x);  // row_bcast15
  x = dpp_add<0x143>(x);  // row_bcast31
  return __int_as_float(__builtin_amdgcn_readlane(__float_as_int(x), 63));
}

__device__ __forceinline__ float dot4(const float4& a, const float4& b) {
  return (a.x*b.x + a.y*b.y) + (a.z*b.z + a.w*b.w);
}

__device__ __forceinline__ float rdlane(float x, int idx) {
  return __int_as_float(__builtin_amdgcn_readlane(__float_as_int(x), idx));
}

// ---------------- Tiled f32 GEMM with fused epilogues (unchanged) ----------
__global__ __launch_bounds__(256) void gemm_multi(const float* __restrict__ X,
                                                  int pbase, GArgs ga) {
  const int p = pbase + blockIdx.y;
  const float* __restrict__ Wp = ga.W[p];
  const float* __restrict__ bp = ga.bias[p];
  const int rowBase = blockIdx.x * 64;
  const int tid = threadIdx.x;
  const int tx = tid & 15;
  const int ty = tid >> 4;

  __shared__ float xs[64][33];
  __shared__ float wsm[256][33];

  float acc[4][16];
  #pragma unroll
  for (int r = 0; r < 4; ++r)
    #pragma unroll
    for (int c = 0; c < 16; ++c) acc[r][c] = bp[tx + 16*c];

  for (int k0 = 0; k0 < C_; k0 += 32) {
    #pragma unroll
    for (int pass = 0; pass < 2; ++pass) {
      int flat = (pass*256 + tid) * 4;
      int r = flat >> 5, kk = flat & 31;
      const float4 v = *(const float4*)(X + (size_t)(rowBase + r)*C_ + k0 + kk);
      xs[r][kk] = v.x; xs[r][kk+1] = v.y; xs[r][kk+2] = v.z; xs[r][kk+3] = v.w;
    }
    #pragma unroll
    for (int pass = 0; pass < 8; ++pass) {
      int flat = (pass*256 + tid) * 4;
      int c = flat >> 5, kk = flat & 31;
      const float4 v = *(const float4*)(Wp + (size_t)c*C_ + k0 + kk);
      wsm[c][kk] = v.x; wsm[c][kk+1] = v.y; wsm[c][kk+2] = v.z; wsm[c][kk+3] = v.w;
    }
    __syncthreads();
    #pragma unroll
    for (int kk = 0; kk < 32; ++kk) {
      float xr[4];
      #pragma unroll
      for (int r = 0; r < 4; ++r) xr[r] = xs[ty*4 + r][kk];
      #pragma unroll
      for (int c = 0; c < 16; ++c) {
        float wv = wsm[tx + 16*c][kk];
        #pragma unroll
        for (int r = 0; r < 4; ++r) acc[r][c] += xr[r] * wv;
      }
    }
    __syncthreads();
  }

  if (p <= 2) {
    float part[4] = {0.f, 0.f, 0.f, 0.f};
    #pragma unroll
    for (int r = 0; r < 4; ++r)
      #pragma unroll
      for (int c = 0; c < 16; ++c) {
        float y = acc[r][c];
        float s = y / (1.f + __expf(-y));
        acc[r][c] = s;
        part[r] += s * s;
      }
    float* outp = (p == 0) ? ga.outQ : (p == 1) ? ga.outK : ga.outV;
    if (p == 2) {
      #pragma unroll
      for (int r = 0; r < 4; ++r)
        #pragma unroll
        for (int c = 0; c < 16; ++c)
          outp[(size_t)(rowBase + ty*4 + r)*C_ + tx + 16*c] = acc[r][c];
    } else {
      __syncthreads();
      float* red = &xs[0][0];
      float* rnorm = &wsm[0][0];
      #pragma unroll
      for (int r = 0; r < 4; ++r) red[(ty*4 + r)*17 + tx] = part[r];
      __syncthreads();
      if (tid < 64) {
        float s = 0.f;
        #pragma unroll
        for (int i = 0; i < 16; ++i) s += red[tid*17 + i];
        rnorm[tid] = 1.f / (sqrtf(s) + 1e-6f);
      }
      __syncthreads();
      #pragma unroll
      for (int r = 0; r < 4; ++r) {
        float sc = rnorm[ty*4 + r];
        #pragma unroll
        for (int c = 0; c < 16; ++c)
          outp[(size_t)(rowBase + ty*4 + r)*C_ + tx + 16*c] = acc[r][c] * sc;
      }
    }
  } else if (p <= 4) {
    float part[4] = {0.f, 0.f, 0.f, 0.f};
    #pragma unroll
    for (int r = 0; r < 4; ++r)
      #pragma unroll
      for (int c = 0; c < 16; ++c) {
        float y = acc[r][c];
        part[r] += 1.f / (1.f + __expf(-y));
      }
    __syncthreads();
    float* red = &xs[0][0];
    #pragma unroll
    for (int r = 0; r < 4; ++r) red[(ty*4 + r)*17 + tx] = part[r];
    __syncthreads();
    if (tid < 64) {
      float s = 0.f;
      #pragma unroll
      for (int i = 0; i < 16; ++i) s += red[tid*17 + i];
      ((p == 3) ? ga.outA : ga.outB)[rowBase + tid] = s * (1.f / 256.f);
    }
  } else {
    #pragma unroll
    for (int r = 0; r < 4; ++r)
      #pragma unroll
      for (int c = 0; c < 16; ++c)
        ga.outO[(size_t)(rowBase + ty*4 + r)*C_ + tx + 16*c] = acc[r][c];
  }
}

// ---------------- kq[t] = dot(k_t, q_t) ------------------------------------
__global__ __launch_bounds__(256) void kq_kernel(const float* __restrict__ kn,
                                                 const float* __restrict__ qn,
                                                 float* __restrict__ kq) {
  const int wave = threadIdx.x >> 6, lane = threadIdx.x & 63;
  const int tok = blockIdx.x * 4 + wave;
  const float4 kv = *(const float4*)(kn + (size_t)tok*C_ + lane*4);
  const float4 qv = *(const float4*)(qn + (size_t)tok*C_ + lane*4);
  float d = red64(dot4(kv, qv));
  if (lane == 0) kq[tok] = d;
}

// ---------------- Sequential gated delta scan ------------------------------
// 16 lanes per state row, 4 rows per wave, 512 waves, XCD-swizzled batches.
// KEY: no wave-uniform loads inside the step loop (they become s_load/SMEM,
// whose out-of-order returns force a full lgkmcnt(0) drain every step).
// a/b/kq are staged 64 steps at a time via coalesced VECTOR loads into
// per-lane registers and extracted per step with v_readlane.
__global__ __launch_bounds__(64) void scan_kernel(const float* __restrict__ qn,
                                                  const float* __restrict__ kn,
                                                  const float* __restrict__ vn,
                                                  float* __restrict__ Oout,
                                                  const float* __restrict__ Ag,
                                                  const float* __restrict__ Bg,
                                                  const float* __restrict__ KQ) {
  const int wg = blockIdx.x;
  const int b = wg & 7;                 // XCD-aligned batch
  const int jbase = (wg >> 3) << 2;     // 4 rows per wave
  const int lane = threadIdx.x & 63;
  const int g = lane & 15;              // column group: cols g*16 .. g*16+15
  const int r = lane >> 4;              // row within wave
  const int j = jbase + r;
  const float* __restrict__ qb = qn + (size_t)b*N_*C_;
  const float* __restrict__ kb = kn + (size_t)b*N_*C_;
  const float* __restrict__ vb = vn + (size_t)b*N_*C_;
  float* __restrict__ Ob = Oout + (size_t)b*N_*C_;
  const float* __restrict__ Ab = Ag + (size_t)b*N_;
  const float* __restrict__ Bb = Bg + (size_t)b*N_;
  const float* __restrict__ Kq = KQ + (size_t)b*N_;
  const int col = g << 4;

  float4 S[4];
  #pragma unroll
  for (int m = 0; m < 4; ++m) S[m] = make_float4(0.f, 0.f, 0.f, 0.f);

  // k/q/v prefetch pipeline: slot d holds step t+d (static indexing only)
  float4 nk[PFD][4], nq[PFD][4];
  float nv[PFD];
  #pragma unroll
  for (int d = 0; d < PFD; ++d) {
    const float* kp = kb + (size_t)d*C_ + col;
    const float* qp = qb + (size_t)d*C_ + col;
    #pragma unroll
    for (int m = 0; m < 4; ++m) {
      nk[d][m] = *(const float4*)(kp + 4*m);
      nq[d][m] = *(const float4*)(qp + 4*m);
    }
    nv[d] = vb[(size_t)d*C_ + j];
  }

  float sa = 0.f, sbg = 0.f, skq = 0.f;   // 64-step scalar stage (per lane)

  for (int t = 0; t < N_; t += PFD) {
    if ((t & 63) == 0) {
      // coalesced vector loads; one trip per 64 steps, no SMEM in the loop
      sa  = Ab[t + lane];
      sbg = Bb[t + lane];
      skq = Kq[t + lane];
    }
    const int tbase = t & 63;
    #pragma unroll
    for (int d = 0; d < PFD; ++d) {
      // per-step uniform scalars via readlane (VALU, no memory)
      const float ca  = rdlane(sa,  tbase + d);
      const float cb  = rdlane(sbg, tbase + d);
      const float ckq = rdlane(skq, tbase + d);

      // consume slot d (= step t+d)
      float4 ck[4], cq[4];
      #pragma unroll
      for (int m = 0; m < 4; ++m) { ck[m] = nk[d][m]; cq[m] = nq[d][m]; }
      const float cv = nv[d];

      // refill slot d with step t+d+PFD
      int tn = t + d + PFD; if (tn > N_ - 1) tn = N_ - 1;
      const float* kp = kb + (size_t)tn*C_ + col;
      const float* qp = qb + (size_t)tn*C_ + col;
      #pragma unroll
      for (int m = 0; m < 4; ++m) {
        nk[d][m] = *(const float4*)(kp + 4*m);
        nq[d][m] = *(const float4*)(qp + 4*m);
      }
      nv[d] = vb[(size_t)tn*C_ + j];

      // per-row partial dots (16 cols per lane), 4-level DPP reduce
      float pk = (dot4(S[0], ck[0]) + dot4(S[1], ck[1]))
               + (dot4(S[2], ck[2]) + dot4(S[3], ck[3]));
      float pq = (dot4(S[0], cq[0]) + dot4(S[1], cq[1]))
               + (dot4(S[2], cq[2]) + dot4(S[3], cq[3]));
      pk = red16(pk);
      pq = red16(pq);

      const float c = cb*cv - ca*cb*pk;
      const float o = ca*pq + c*ckq;
      #pragma unroll
      for (int m = 0; m < 4; ++m) {
        S[m].x = ca*S[m].x + c*ck[m].x;
        S[m].y = ca*S[m].y + c*ck[m].y;
        S[m].z = ca*S[m].z + c*ck[m].z;
        S[m].w = ca*S[m].w + c*ck[m].w;
      }
      if (g == 0) Ob[(size_t)(t + d)*C_ + j] = o;
    }
  }
}

extern "C" void kernel_launch(void* const* d_in, const int* in_sizes, int n_in,
                              void* d_out, int out_size, void* d_ws, size_t ws_size,
                              hipStream_t stream) {
  const float* x  = (const float*)d_in[0];
  const float* Wq = (const float*)d_in[1];  const float* bq = (const float*)d_in[2];
  const float* Wk = (const float*)d_in[3];  const float* bk = (const float*)d_in[4];
  const float* Wv = (const float*)d_in[5];  const float* bv = (const float*)d_in[6];
  const float* Wa = (const float*)d_in[7];  const float* ba = (const float*)d_in[8];
  const float* Wb = (const float*)d_in[9];  const float* bb = (const float*)d_in[10];
  const float* Wo = (const float*)d_in[11]; const float* bo = (const float*)d_in[12];

  float* ws = (float*)d_ws;
  float* qn = ws;
  float* kn = ws + (size_t)TOK*C_;
  float* vO = ws + 2*(size_t)TOK*C_;
  float* Ag = ws + 3*(size_t)TOK*C_;
  float* Bg = Ag + TOK;
  float* KQ = Bg + TOK;
  float* Obuf = (float*)d_out;   // scan output staged in d_out, then
                                 // overwritten in place by the final GEMM

  GArgs ga;
  ga.W[0] = Wq; ga.W[1] = Wk; ga.W[2] = Wv; ga.W[3] = Wa; ga.W[4] = Wb; ga.W[5] = Wo;
  ga.bias[0] = bq; ga.bias[1] = bk; ga.bias[2] = bv; ga.bias[3] = ba; ga.bias[4] = bb; ga.bias[5] = bo;
  ga.outQ = qn; ga.outK = kn; ga.outV = vO; ga.outA = Ag; ga.outB = Bg;
  ga.outO = (float*)d_out;

  gemm_multi<<<dim3(TOK/64, 5), 256, 0, stream>>>(x, 0, ga);
  kq_kernel<<<dim3(TOK/4), 256, 0, stream>>>(kn, qn, KQ);
  scan_kernel<<<dim3(B_*64), 64, 0, stream>>>(qn, kn, vO, Obuf, Ag, Bg, KQ);
  gemm_multi<<<dim3(TOK/64, 1), 256, 0, stream>>>(Obuf, 5, ga);
}

// Round 6
// 864.168 us; speedup vs baseline: 1.0383x; 1.0383x over previous
//
#include <hip/hip_runtime.h>
#include <math.h>

#define B_ 8
#define N_ 2048
#define C_ 256
#define TOK (B_*N_)
#define PFD 8   // scan prefetch depth (steps)

struct GArgs {
  const float* W[6];
  const float* bias[6];
  float* outQ; float* outK; float* outV; float* outA; float* outB; float* outO;
};

// ---------------- DPP cross-lane reduction helpers (all-VALU, no DS) -------
template<int CTRL>
__device__ __forceinline__ float dpp_add(float x) {
  int r = __builtin_amdgcn_update_dpp(0, __float_as_int(x), CTRL, 0xF, 0xF, true);
  return x + __int_as_float(r);
}
// Sum across each aligned 16-lane group; result broadcast to all 16 lanes.
__device__ __forceinline__ float red16(float x) {
  x = dpp_add<0xB1>(x);   // quad_perm [1,0,3,2]  (xor 1)
  x = dpp_add<0x4E>(x);   // quad_perm [2,3,0,1]  (xor 2)
  x = dpp_add<0x140>(x);  // row_mirror           (xor 15)
  x = dpp_add<0x141>(x);  // row_half_mirror      (xor 7)
  return x;
}
// Full 64-lane sum -> scalar (valid in all lanes via readlane of lane 63).
__device__ __forceinline__ float red64(float x) {
  x = red16(x);
  x = dpp_add<0x142>(x);  // row_bcast15
  x = dpp_add<0x143>(x);  // row_bcast31  (lanes 48-63 hold full sum)
  return __int_as_float(__builtin_amdgcn_readlane(__float_as_int(x), 63));
}

__device__ __forceinline__ float dot4(const float4& a, const float4& b) {
  return (a.x*b.x + a.y*b.y) + (a.z*b.z + a.w*b.w);
}

__device__ __forceinline__ float rdlane(float x, int idx) {
  return __int_as_float(__builtin_amdgcn_readlane(__float_as_int(x), idx));
}

// ---------------- Tiled f32 GEMM with fused epilogues (unchanged) ----------
__global__ __launch_bounds__(256) void gemm_multi(const float* __restrict__ X,
                                                  int pbase, GArgs ga) {
  const int p = pbase + blockIdx.y;
  const float* __restrict__ Wp = ga.W[p];
  const float* __restrict__ bp = ga.bias[p];
  const int rowBase = blockIdx.x * 64;
  const int tid = threadIdx.x;
  const int tx = tid & 15;
  const int ty = tid >> 4;

  __shared__ float xs[64][33];
  __shared__ float wsm[256][33];

  float acc[4][16];
  #pragma unroll
  for (int r = 0; r < 4; ++r)
    #pragma unroll
    for (int c = 0; c < 16; ++c) acc[r][c] = bp[tx + 16*c];

  for (int k0 = 0; k0 < C_; k0 += 32) {
    #pragma unroll
    for (int pass = 0; pass < 2; ++pass) {
      int flat = (pass*256 + tid) * 4;
      int r = flat >> 5, kk = flat & 31;
      const float4 v = *(const float4*)(X + (size_t)(rowBase + r)*C_ + k0 + kk);
      xs[r][kk] = v.x; xs[r][kk+1] = v.y; xs[r][kk+2] = v.z; xs[r][kk+3] = v.w;
    }
    #pragma unroll
    for (int pass = 0; pass < 8; ++pass) {
      int flat = (pass*256 + tid) * 4;
      int c = flat >> 5, kk = flat & 31;
      const float4 v = *(const float4*)(Wp + (size_t)c*C_ + k0 + kk);
      wsm[c][kk] = v.x; wsm[c][kk+1] = v.y; wsm[c][kk+2] = v.z; wsm[c][kk+3] = v.w;
    }
    __syncthreads();
    #pragma unroll
    for (int kk = 0; kk < 32; ++kk) {
      float xr[4];
      #pragma unroll
      for (int r = 0; r < 4; ++r) xr[r] = xs[ty*4 + r][kk];
      #pragma unroll
      for (int c = 0; c < 16; ++c) {
        float wv = wsm[tx + 16*c][kk];
        #pragma unroll
        for (int r = 0; r < 4; ++r) acc[r][c] += xr[r] * wv;
      }
    }
    __syncthreads();
  }

  if (p <= 2) {
    float part[4] = {0.f, 0.f, 0.f, 0.f};
    #pragma unroll
    for (int r = 0; r < 4; ++r)
      #pragma unroll
      for (int c = 0; c < 16; ++c) {
        float y = acc[r][c];
        float s = y / (1.f + __expf(-y));
        acc[r][c] = s;
        part[r] += s * s;
      }
    float* outp = (p == 0) ? ga.outQ : (p == 1) ? ga.outK : ga.outV;
    if (p == 2) {
      #pragma unroll
      for (int r = 0; r < 4; ++r)
        #pragma unroll
        for (int c = 0; c < 16; ++c)
          outp[(size_t)(rowBase + ty*4 + r)*C_ + tx + 16*c] = acc[r][c];
    } else {
      __syncthreads();
      float* red = &xs[0][0];
      float* rnorm = &wsm[0][0];
      #pragma unroll
      for (int r = 0; r < 4; ++r) red[(ty*4 + r)*17 + tx] = part[r];
      __syncthreads();
      if (tid < 64) {
        float s = 0.f;
        #pragma unroll
        for (int i = 0; i < 16; ++i) s += red[tid*17 + i];
        rnorm[tid] = 1.f / (sqrtf(s) + 1e-6f);
      }
      __syncthreads();
      #pragma unroll
      for (int r = 0; r < 4; ++r) {
        float sc = rnorm[ty*4 + r];
        #pragma unroll
        for (int c = 0; c < 16; ++c)
          outp[(size_t)(rowBase + ty*4 + r)*C_ + tx + 16*c] = acc[r][c] * sc;
      }
    }
  } else if (p <= 4) {
    float part[4] = {0.f, 0.f, 0.f, 0.f};
    #pragma unroll
    for (int r = 0; r < 4; ++r)
      #pragma unroll
      for (int c = 0; c < 16; ++c) {
        float y = acc[r][c];
        part[r] += 1.f / (1.f + __expf(-y));
      }
    __syncthreads();
    float* red = &xs[0][0];
    #pragma unroll
    for (int r = 0; r < 4; ++r) red[(ty*4 + r)*17 + tx] = part[r];
    __syncthreads();
    if (tid < 64) {
      float s = 0.f;
      #pragma unroll
      for (int i = 0; i < 16; ++i) s += red[tid*17 + i];
      ((p == 3) ? ga.outA : ga.outB)[rowBase + tid] = s * (1.f / 256.f);
    }
  } else {
    #pragma unroll
    for (int r = 0; r < 4; ++r)
      #pragma unroll
      for (int c = 0; c < 16; ++c)
        ga.outO[(size_t)(rowBase + ty*4 + r)*C_ + tx + 16*c] = acc[r][c];
  }
}

// ---------------- kq[t] = dot(k_t, q_t) ------------------------------------
__global__ __launch_bounds__(256) void kq_kernel(const float* __restrict__ kn,
                                                 const float* __restrict__ qn,
                                                 float* __restrict__ kq) {
  const int wave = threadIdx.x >> 6, lane = threadIdx.x & 63;
  const int tok = blockIdx.x * 4 + wave;
  const float4 kv = *(const float4*)(kn + (size_t)tok*C_ + lane*4);
  const float4 qv = *(const float4*)(qn + (size_t)tok*C_ + lane*4);
  float d = red64(dot4(kv, qv));
  if (lane == 0) kq[tok] = d;
}

// ---------------- Sequential gated delta scan (thin-wave) ------------------
// ONE 64-lane wave per state row j: 4 cols/lane, full-wave DPP reduce.
// 2048 waves total = 8 waves/CU (4x the TLP of the old shape) and only
// 2 float4 loads per step per wave (zero redundancy), staying far below
// any per-wave outstanding-VMEM cap; PFD=8 register slots cover latency.
// a/b/kq/v are staged 64 steps at a time via vector loads + v_readlane
// (no wave-uniform s_loads in the loop), double-buffered (A=current block,
// B=next block, rotated by register copies -- no dynamic indexing).
__global__ __launch_bounds__(64) void scan_kernel(const float* __restrict__ qn,
                                                  const float* __restrict__ kn,
                                                  const float* __restrict__ vn,
                                                  float* __restrict__ Oout,
                                                  const float* __restrict__ Ag,
                                                  const float* __restrict__ Bg,
                                                  const float* __restrict__ KQ) {
  const int wg = blockIdx.x;
  const int b = wg & 7;                 // XCD-aligned batch
  const int j = wg >> 3;                // state row 0..255
  const int lane = threadIdx.x & 63;
  const int col = lane * 4;
  const float* __restrict__ qb = qn + (size_t)b*N_*C_;
  const float* __restrict__ kb = kn + (size_t)b*N_*C_;
  const float* __restrict__ vb = vn + (size_t)b*N_*C_;
  float* __restrict__ Ob = Oout + (size_t)b*N_*C_;
  const float* __restrict__ Ab = Ag + (size_t)b*N_;
  const float* __restrict__ Bb = Bg + (size_t)b*N_;
  const float* __restrict__ Kq = KQ + (size_t)b*N_;

  float4 S = make_float4(0.f, 0.f, 0.f, 0.f);

  // k/q prefetch slots: nk[d]/nq[d] hold step t+d (static indexing only)
  float4 nk[PFD], nq[PFD];
  #pragma unroll
  for (int d = 0; d < PFD; ++d) {
    nk[d] = *(const float4*)(kb + (size_t)d*C_ + col);
    nq[d] = *(const float4*)(qb + (size_t)d*C_ + col);
  }

  // 64-step scalar stages (per-lane vector loads, consumed via readlane)
  float saA = Ab[lane],      sbA = Bb[lane],      skqA = Kq[lane];
  float svA = vb[(size_t)lane*C_ + j];
  float saB = Ab[64 + lane], sbB = Bb[64 + lane], skqB = Kq[64 + lane];
  float svB = vb[(size_t)(64 + lane)*C_ + j];

  for (int t0 = 0; t0 < N_; t0 += 64) {
    for (int tt = 0; tt < 64; tt += PFD) {
      #pragma unroll
      for (int d = 0; d < PFD; ++d) {
        const int ti = tt + d;              // index within block (uniform)
        const float ca  = rdlane(saA,  ti);
        const float cbg = rdlane(sbA,  ti);
        const float ckq = rdlane(skqA, ti);
        const float cv  = rdlane(svA,  ti);

        const float4 ck = nk[d];            // keep k for the state update
        float pk = dot4(S, ck);
        float pq = dot4(S, nq[d]);          // q dead after dot -> no copy

        // refill slot d with step t0+tt+d+PFD
        int tn = t0 + tt + d + PFD; if (tn > N_ - 1) tn = N_ - 1;
        nk[d] = *(const float4*)(kb + (size_t)tn*C_ + col);
        nq[d] = *(const float4*)(qb + (size_t)tn*C_ + col);

        pk = red64(pk);
        pq = red64(pq);

        const float c = cbg*cv - ca*cbg*pk;
        const float o = ca*pq + c*ckq;
        S.x = ca*S.x + c*ck.x;
        S.y = ca*S.y + c*ck.y;
        S.z = ca*S.z + c*ck.z;
        S.w = ca*S.w + c*ck.w;
        if (lane == 0) Ob[(size_t)(t0 + tt + d)*C_ + j] = o;
      }
    }
    // rotate stages: A <- B, issue B <- block after next (clamped)
    saA = saB; sbA = sbB; skqA = skqB; svA = svB;
    int nt0 = t0 + 128; if (nt0 > N_ - 64) nt0 = N_ - 64;
    saB  = Ab[nt0 + lane];
    sbB  = Bb[nt0 + lane];
    skqB = Kq[nt0 + lane];
    svB  = vb[(size_t)(nt0 + lane)*C_ + j];
  }
}

extern "C" void kernel_launch(void* const* d_in, const int* in_sizes, int n_in,
                              void* d_out, int out_size, void* d_ws, size_t ws_size,
                              hipStream_t stream) {
  const float* x  = (const float*)d_in[0];
  const float* Wq = (const float*)d_in[1];  const float* bq = (const float*)d_in[2];
  const float* Wk = (const float*)d_in[3];  const float* bk = (const float*)d_in[4];
  const float* Wv = (const float*)d_in[5];  const float* bv = (const float*)d_in[6];
  const float* Wa = (const float*)d_in[7];  const float* ba = (const float*)d_in[8];
  const float* Wb = (const float*)d_in[9];  const float* bb = (const float*)d_in[10];
  const float* Wo = (const float*)d_in[11]; const float* bo = (const float*)d_in[12];

  float* ws = (float*)d_ws;
  float* qn = ws;
  float* kn = ws + (size_t)TOK*C_;
  float* vO = ws + 2*(size_t)TOK*C_;
  float* Ag = ws + 3*(size_t)TOK*C_;
  float* Bg = Ag + TOK;
  float* KQ = Bg + TOK;
  float* Obuf = (float*)d_out;   // scan output staged in d_out, then
                                 // overwritten in place by the final GEMM

  GArgs ga;
  ga.W[0] = Wq; ga.W[1] = Wk; ga.W[2] = Wv; ga.W[3] = Wa; ga.W[4] = Wb; ga.W[5] = Wo;
  ga.bias[0] = bq; ga.bias[1] = bk; ga.bias[2] = bv; ga.bias[3] = ba; ga.bias[4] = bb; ga.bias[5] = bo;
  ga.outQ = qn; ga.outK = kn; ga.outV = vO; ga.outA = Ag; ga.outB = Bg;
  ga.outO = (float*)d_out;

  gemm_multi<<<dim3(TOK/64, 5), 256, 0, stream>>>(x, 0, ga);
  kq_kernel<<<dim3(TOK/4), 256, 0, stream>>>(kn, qn, KQ);
  scan_kernel<<<dim3(B_*256), 64, 0, stream>>>(qn, kn, vO, Obuf, Ag, Bg, KQ);
  gemm_multi<<<dim3(TOK/64, 1), 256, 0, stream>>>(Obuf, 5, ga);
}